// Round 10
// baseline (284.928 us; speedup 1.0000x reference)
//
#include <hip/hip_runtime.h>
#include <hip/hip_bf16.h>
#include <stdint.h>

#define NN 131072

typedef unsigned int uint;
typedef unsigned short ushort;
typedef __attribute__((ext_vector_type(8))) __bf16 bf16x8;
typedef __attribute__((ext_vector_type(2))) __bf16 bf16x2;
typedef __attribute__((ext_vector_type(4))) float f32x4;

// ---------------- ws layout (bytes) ----------------
// 0: meta (cntNZ, cntF, cntA)
// 1K: scale(256f), 2K: shift(256f), 3K: cf(256f)
// 8K: cntM[512], 12K: baseA[512], 16K: baseF[512]
// 32K: Bwa packed (256 cols x K=256 bf16) = 128KB
// 256K: Bwf packed (256 cols x K=768 bf16) = 384KB  [k<512: Wvf, k>=512: Wf_top]
// 1M: fusedIdx (512KB), 1.5M: audioIdx (512KB)
// 8M: bn_s (4098*256 f32 = 4.2MB), 16M: bn_q
// 32M: gf bf16 (NN*256 = 64MB)

#define NB_MAIN 4098

__device__ __forceinline__ ushort f2bf(float f) {
    uint u = __float_as_uint(f);
    u += 0x7FFF + ((u >> 16) & 1);
    return (ushort)(u >> 16);
}
__device__ __forceinline__ uint pk2(float a, float b) {
    bf16x2 t;
    t[0] = (__bf16)a;
    t[1] = (__bf16)b;
    return __builtin_bit_cast(uint, t);
}
__device__ __forceinline__ bool mask_val(const unsigned char* m8, int flag, int i) {
    return flag ? (m8[(size_t)i * 4] != 0) : (m8[i] != 0);
}
// Packed B layout: fragment chunk (kb = k>>5, ct = c>>4) is 512 contiguous
// ushorts in exact MFMA-lane order: lane = fg*16+fr, elem = k&7.
__device__ __forceinline__ size_t pack_off(int k, int c) {
    return (size_t)(((k >> 5) * 16 + (c >> 4)) * 512
                    + (((k >> 3) & 3) * 16 + (c & 15)) * 8 + (k & 7));
}

// Detect mask dtype: nonzero bytes at offset 1 (mod 4) => 1-byte bool.
__global__ void k_detect(const uint4* m128, int n, int* cntNZ) {
    __shared__ int cnt;
    if (threadIdx.x == 0) cnt = 0;
    __syncthreads();
    int local = 0;
    int nv = n >> 4;
    #pragma unroll 4
    for (int i = threadIdx.x; i < nv; i += 256) {
        uint4 v = m128[i];
        if ((v.x | v.y | v.z | v.w) & 0x0000FF00u) local = 1;
    }
    if (local) atomicAdd(&cnt, 1);
    __syncthreads();
    if (threadIdx.x == 0) *cntNZ = cnt;
}

// Per-256-row-chunk audio count.
__global__ void k_count(const unsigned char* m8, const int* cntNZp, int* cntM) {
    int flag = (*cntNZp == 0) ? 1 : 0;
    int t = threadIdx.x;
    bool m = mask_val(m8, flag, blockIdx.x * 256 + t);
    unsigned long long bal = __ballot(m);
    __shared__ int wsum[4];
    if ((t & 63) == 0) wsum[t >> 6] = __popcll(bal);
    __syncthreads();
    if (t == 0) cntM[blockIdx.x] = wsum[0] + wsum[1] + wsum[2] + wsum[3];
}

// Exclusive scan of chunk counts -> bases + totals. One block, 512 threads.
__global__ void k_scan(const int* __restrict__ cntM, int* __restrict__ meta,
                       int* __restrict__ baseA, int* __restrict__ baseF) {
    __shared__ int sA[512], sF[512];
    int t = threadIdx.x;
    int a = cntM[t], f = 256 - a;
    sA[t] = a; sF[t] = f;
    __syncthreads();
    for (int off = 1; off < 512; off <<= 1) {
        int va = (t >= off) ? sA[t - off] : 0;
        int vf = (t >= off) ? sF[t - off] : 0;
        __syncthreads();
        sA[t] += va; sF[t] += vf;
        __syncthreads();
    }
    baseA[t] = sA[t] - a;
    baseF[t] = sF[t] - f;
    if (t == 511) { meta[2] = sA[511]; meta[1] = sF[511]; }
}

// Stable partition fill.
__global__ void k_fill(const unsigned char* m8, const int* cntNZp,
                       const int* __restrict__ baseA, const int* __restrict__ baseF,
                       int* __restrict__ audioIdx, int* __restrict__ fusedIdx) {
    int flag = (*cntNZp == 0) ? 1 : 0;
    int blk = blockIdx.x, t = threadIdx.x;
    int row = blk * 256 + t;
    bool m = mask_val(m8, flag, row);
    unsigned long long bal = __ballot(m);
    int lane = t & 63, w = t >> 6;
    unsigned long long lt = (1ull << lane) - 1ull;
    int pA = __popcll(bal & lt);
    __shared__ int wA[4];
    if (lane == 0) wA[w] = __popcll(bal);
    __syncthreads();
    int offA = 0;
    for (int i = 0; i < w; ++i) offA += wA[i];
    int offF = w * 64 - offA;
    int pF = lane - pA;
    if (m) audioIdx[baseA[blk] + offA + pA] = row;
    else   fusedIdx[baseF[blk] + offF + pF] = row;
}

// Build packed weights. Bwa: k<256 -> Wa[k][c].
// Bwf (fused, K=768, order [v_in|a_in]): k<512 -> (Wv@Wf_bot)[k][c];
// k in [512,768) -> Wf[k-512][c]. Block 1024 computes c_f.
__global__ void k_prep(const float* __restrict__ Wa, const float* __restrict__ Wf,
                       const float* __restrict__ Wv, const float* __restrict__ bv,
                       const float* __restrict__ bf_, ushort* __restrict__ Bwa,
                       ushort* __restrict__ Bwf, float* __restrict__ cf) {
    int c = threadIdx.x;
    int b = blockIdx.x;
    if (b < 256) {
        Bwa[pack_off(b, c)] = f2bf(Wa[b * 256 + c]);
    } else if (b < 512) {
        Bwf[pack_off(512 + (b - 256), c)] = f2bf(Wf[(b - 256) * 256 + c]);
    } else if (b < 1024) {
        int k = b - 512;
        const float* wr = Wv + k * 256;
        float acc = 0.f;
        #pragma unroll 8
        for (int j = 0; j < 256; ++j) acc += wr[j] * Wf[(256 + j) * 256 + c];
        Bwf[pack_off(k, c)] = f2bf(acc);
    } else {
        float acc = bf_[c];
        #pragma unroll 8
        for (int j = 0; j < 256; ++j) acc += bv[j] * Wf[(256 + j) * 256 + c];
        cf[c] = acc;
    }
}

// Panel-staged role-split GEMM. BM=32, BN=256, 8 waves (2x4).
// Phase 1: stage the whole A-panel (32 rows x K bf16, XOR-swizzled) in LDS via
// one streaming pass (wave-per-4-rows, contiguous 1KB loads, nontemporal);
// sim computed in-register per row. Phase 2: barrier-free K-loop, A from LDS,
// B direct from packed L2-resident buffers. Epilogue: bias, gf scatter, BN.
__global__ __launch_bounds__(512, 4) void k_main(
    const float* __restrict__ x, const int* __restrict__ meta,
    const int* __restrict__ fusedIdx, const int* __restrict__ audioIdx,
    const ushort* __restrict__ Bwa, const ushort* __restrict__ Bwf,
    const float* __restrict__ ba, const float* __restrict__ cf,
    ushort* __restrict__ gf, float* __restrict__ bn_s, float* __restrict__ bn_q)
{
    __shared__ ushort panel[32 * 768];   // 48KB
    __shared__ int ridxS[32];
    __shared__ unsigned char validS[32];
    __shared__ float redS[256], redQ[256];

    const int tid = threadIdx.x;
    const int cntF = meta[1], cntA = meta[2];
    const int nbF = (cntF + 31) >> 5;
    const int nbA = (cntA + 31) >> 5;
    const int b = blockIdx.x;
    const bool isF = b < nbF;
    const int bb = isF ? b : b - nbF;

    if (!isF && bb >= nbA) {   // idle block: zero BN slots
        if (tid < 256) {
            bn_s[(size_t)b * 256 + tid] = 0.f;
            bn_q[(size_t)b * 256 + tid] = 0.f;
        }
        return;
    }

    const int cnt = isF ? cntF : cntA;
    const int* idxArr = isF ? fusedIdx : audioIdx;
    const int lane = tid & 63;
    const int w = tid >> 6, wr = w >> 2, wc = w & 3;
    const int fr = lane & 15, fg = lane >> 4;

    if (tid < 32) {
        int gpos = bb * 32 + tid;
        int ok = gpos < cnt;
        ridxS[tid] = ok ? idxArr[gpos] : 0;
        validS[tid] = ok;
    }
    if (tid < 256) { redS[tid] = 0.f; redQ[tid] = 0.f; }
    __syncthreads();

    // ---- phase 1: stream rows -> sim -> pack -> LDS panel ----
    {
        const int sw = lane >> 1;            // 16B slot within 32-slot group
        const int o4 = (lane & 1) * 4;       // ushort offset within slot
        #pragma unroll 2
        for (int rr = 0; rr < 4; ++rr) {
            int r = w * 4 + rr;
            const f32x4* bp = (const f32x4*)(x + (size_t)ridxS[r] * 2048);
            float sv = validS[r] ? 1.f : 0.f;
            ushort* prow = panel + r * 768;
            int rx = r & 7;
            if (isF) {
                f32x4 ta = __builtin_nontemporal_load(bp + lane);        // a_in
                f32x4 t0 = __builtin_nontemporal_load(bp + 128 + lane);  // v_in lo
                f32x4 t1 = __builtin_nontemporal_load(bp + 192 + lane);  // v_in hi
                f32x4 t2 = __builtin_nontemporal_load(bp + 256 + lane);  // a_vf lo
                f32x4 t3 = __builtin_nontemporal_load(bp + 320 + lane);  // a_vf hi
                f32x4 t4 = __builtin_nontemporal_load(bp + 384 + lane);  // v_vf lo
                f32x4 t5 = __builtin_nontemporal_load(bp + 448 + lane);  // v_vf hi
                float dot = t2.x * t4.x + t2.y * t4.y + t2.z * t4.z + t2.w * t4.w
                          + t3.x * t5.x + t3.y * t5.y + t3.z * t5.z + t3.w * t5.w;
                float na = t2.x * t2.x + t2.y * t2.y + t2.z * t2.z + t2.w * t2.w
                         + t3.x * t3.x + t3.y * t3.y + t3.z * t3.z + t3.w * t3.w;
                float nv = t4.x * t4.x + t4.y * t4.y + t4.z * t4.z + t4.w * t4.w
                         + t5.x * t5.x + t5.y * t5.y + t5.z * t5.z + t5.w * t5.w;
                #pragma unroll
                for (int off = 32; off; off >>= 1) {
                    dot += __shfl_xor(dot, off);
                    na  += __shfl_xor(na,  off);
                    nv  += __shfl_xor(nv,  off);
                }
                float sim = dot / fmaxf(sqrtf(na * nv), 1e-8f);
                float sa = sv * sim;
                uint2 q0 = {pk2(t0.x * sv, t0.y * sv), pk2(t0.z * sv, t0.w * sv)};
                uint2 q1 = {pk2(t1.x * sv, t1.y * sv), pk2(t1.z * sv, t1.w * sv)};
                uint2 qa = {pk2(ta.x * sa, ta.y * sa), pk2(ta.z * sa, ta.w * sa)};
                *(uint2*)(prow + ((sw ^ rx) << 3) + o4)          = q0;  // k 0..255
                *(uint2*)(prow + (((32 + sw) ^ rx) << 3) + o4)   = q1;  // k 256..511
                *(uint2*)(prow + (((64 + sw) ^ rx) << 3) + o4)   = qa;  // k 512..767
            } else {
                f32x4 ta = __builtin_nontemporal_load(bp + lane);        // a_in
                uint2 qa = {pk2(ta.x * sv, ta.y * sv), pk2(ta.z * sv, ta.w * sv)};
                *(uint2*)(prow + ((sw ^ rx) << 3) + o4) = qa;             // k 0..255
            }
        }
    }
    __syncthreads();

    // ---- phase 2: barrier-free K-loop (A: LDS, B: packed L2) ----
    const int NS = isF ? 12 : 4;
    const ushort* bBase = (isF ? Bwf : Bwa) + ((size_t)(wc * 4) << 9) + (lane << 3);
    const int rrd = wr * 16 + fr;
    const ushort* prd = panel + rrd * 768;
    const int rxr = rrd & 7;

    f32x4 acc[4];
    #pragma unroll
    for (int n = 0; n < 4; ++n) acc[n] = (f32x4){0.f, 0.f, 0.f, 0.f};

    for (int st = 0; st < NS; ++st) {
        #pragma unroll
        for (int kk = 0; kk < 2; ++kk) {
            bf16x8 af = *(const bf16x8*)(prd + (((st * 8 + kk * 4 + fg) ^ rxr) << 3));
            #pragma unroll
            for (int n = 0; n < 4; ++n) {
                bf16x8 bv = *(const bf16x8*)(bBase + ((size_t)((st * 2 + kk) * 16 + n) << 9));
                acc[n] = __builtin_amdgcn_mfma_f32_16x16x32_bf16(af, bv, acc[n], 0, 0, 0);
            }
        }
    }

    // ---- epilogue: bias, gf scatter, BN partials ----
    const int colLo = wc * 64 + fr;
    const float* biasp = isF ? cf : ba;
    float bN[4];
    #pragma unroll
    for (int n = 0; n < 4; ++n) bN[n] = biasp[colLo + n * 16];

    float cs[4] = {0.f, 0.f, 0.f, 0.f}, cq[4] = {0.f, 0.f, 0.f, 0.f};
    #pragma unroll
    for (int j = 0; j < 4; ++j) {
        int rloc = wr * 16 + fg * 4 + j;
        if (validS[rloc]) {
            ushort* grow = gf + (size_t)ridxS[rloc] * 256;
            #pragma unroll
            for (int n = 0; n < 4; ++n) {
                float g = acc[n][j] + bN[n];
                grow[colLo + n * 16] = f2bf(g);
                cs[n] += g;
                cq[n] += g * g;
            }
        }
    }
    #pragma unroll
    for (int n = 0; n < 4; ++n) {
        atomicAdd(&redS[colLo + n * 16], cs[n]);
        atomicAdd(&redQ[colLo + n * 16], cq[n]);
    }
    __syncthreads();
    if (tid < 256) {
        bn_s[(size_t)b * 256 + tid] = redS[tid];
        bn_q[(size_t)b * 256 + tid] = redQ[tid];
    }
}

// Finalize BN stats: one block per channel, reduce NB_MAIN block partials.
__global__ void k_stats(const float* __restrict__ bn_s, const float* __restrict__ bn_q,
                        const float* __restrict__ gamma, const float* __restrict__ beta,
                        float* __restrict__ scale, float* __restrict__ shift) {
    int c = blockIdx.x;
    int t = threadIdx.x;
    float s = 0.f, q = 0.f;
    for (int r = t; r < NB_MAIN; r += 256) {
        s += bn_s[(size_t)r * 256 + c];
        q += bn_q[(size_t)r * 256 + c];
    }
    __shared__ float ss[256], qq[256];
    ss[t] = s; qq[t] = q;
    __syncthreads();
    for (int off = 128; off; off >>= 1) {
        if (t < off) { ss[t] += ss[t + off]; qq[t] += qq[t + off]; }
        __syncthreads();
    }
    if (t == 0) {
        float mu  = ss[0] / 131072.f;
        float var = qq[0] / 131072.f - mu * mu;
        float sc = gamma[c] * rsqrtf(var + 1e-5f);
        scale[c] = sc;
        shift[c] = beta[c] - mu * sc;
    }
}

// Normalize + ReLU + 256->2 FC. One wave per row, bf16 gf input.
__global__ void k_out(const ushort* __restrict__ gf, const float* __restrict__ scale,
                      const float* __restrict__ shift, const float* __restrict__ Wfc,
                      const float* __restrict__ bfc, float* __restrict__ out) {
    int wid = threadIdx.x >> 6;
    int lane = threadIdx.x & 63;
    int i = blockIdx.x * 4 + wid;
    uint2 gv = ((const uint2*)(gf + (size_t)i * 256))[lane];
    float g0 = __uint_as_float(gv.x << 16);
    float g1 = __uint_as_float(gv.x & 0xFFFF0000u);
    float g2 = __uint_as_float(gv.y << 16);
    float g3 = __uint_as_float(gv.y & 0xFFFF0000u);
    int c0 = lane * 4;
    float4 sc = *(const float4*)(scale + c0);
    float4 sh = *(const float4*)(shift + c0);
    float y0 = fmaxf(g0 * sc.x + sh.x, 0.f);
    float y1 = fmaxf(g1 * sc.y + sh.y, 0.f);
    float y2 = fmaxf(g2 * sc.z + sh.z, 0.f);
    float y3 = fmaxf(g3 * sc.w + sh.w, 0.f);
    const float4* w = (const float4*)(Wfc + c0 * 2);
    float4 w0 = w[0], w1 = w[1];
    float p0 = y0 * w0.x + y1 * w0.z + y2 * w1.x + y3 * w1.z;
    float p1 = y0 * w0.y + y1 * w0.w + y2 * w1.y + y3 * w1.w;
    #pragma unroll
    for (int off = 32; off; off >>= 1) {
        p0 += __shfl_xor(p0, off);
        p1 += __shfl_xor(p1, off);
    }
    if (lane == 0) {
        out[(size_t)i * 2]     = p0 + bfc[0];
        out[(size_t)i * 2 + 1] = p1 + bfc[1];
    }
}

extern "C" void kernel_launch(void* const* d_in, const int* in_sizes, int n_in,
                              void* d_out, int out_size, void* d_ws, size_t ws_size,
                              hipStream_t stream) {
    const float* x          = (const float*)d_in[0];
    const unsigned char* mk = (const unsigned char*)d_in[1];
    const float* Wa  = (const float*)d_in[2];
    const float* ba  = (const float*)d_in[3];
    const float* Wv  = (const float*)d_in[4];
    const float* bv  = (const float*)d_in[5];
    const float* Wf  = (const float*)d_in[6];
    const float* bf  = (const float*)d_in[7];
    const float* gamma = (const float*)d_in[8];
    const float* beta  = (const float*)d_in[9];
    const float* Wfc = (const float*)d_in[10];
    const float* bfc = (const float*)d_in[11];
    float* out = (float*)d_out;

    char* ws = (char*)d_ws;
    int*    meta   = (int*)ws;                       // cntNZ, cntF, cntA
    float*  scale  = (float*)(ws + 1024);
    float*  shift  = (float*)(ws + 2048);
    float*  cf     = (float*)(ws + 3072);
    int*    cntM   = (int*)(ws + 8192);
    int*    baseA  = (int*)(ws + 12288);
    int*    baseF  = (int*)(ws + 16384);
    ushort* Bwa    = (ushort*)(ws + 32768);
    ushort* Bwf    = (ushort*)(ws + 262144);
    int*    fusedIdx = (int*)(ws + (1u << 20));
    int*    audioIdx = (int*)(ws + (1u << 20) + (512u << 10));
    float*  bn_s   = (float*)(ws + (8u << 20));
    float*  bn_q   = (float*)(ws + (16u << 20));
    ushort* gf     = (ushort*)(ws + (32u << 20));

    int n = in_sizes[1];  // NN

    k_detect<<<1, 256, 0, stream>>>((const uint4*)mk, n, meta);
    k_count<<<512, 256, 0, stream>>>(mk, meta, cntM);
    k_scan<<<1, 512, 0, stream>>>(cntM, meta, baseA, baseF);
    k_fill<<<512, 256, 0, stream>>>(mk, meta, baseA, baseF, audioIdx, fusedIdx);
    k_prep<<<1025, 256, 0, stream>>>(Wa, Wf, Wv, bv, bf, Bwa, Bwf, cf);
    k_main<<<NB_MAIN, 512, 0, stream>>>(x, meta, fusedIdx, audioIdx, Bwa, Bwf, ba, cf,
                                        gf, bn_s, bn_q);
    k_stats<<<256, 256, 0, stream>>>(bn_s, bn_q, gamma, beta, scale, shift);
    k_out<<<NN / 4, 256, 0, stream>>>(gf, scale, shift, Wfc, bfc, out);
}

// Round 11
// 254.193 us; speedup vs baseline: 1.1209x; 1.1209x over previous
//
#include <hip/hip_runtime.h>
#include <hip/hip_bf16.h>
#include <stdint.h>

#define NN 131072
#define NB2 2050   // max fused(2048) + audio(1) + slack

typedef unsigned int uint;
typedef unsigned short ushort;
typedef __attribute__((ext_vector_type(8))) __bf16 bf16x8;
typedef __attribute__((ext_vector_type(2))) __bf16 bf16x2;
typedef __attribute__((ext_vector_type(4))) float f32x4;

// ---------------- ws layout (bytes) ----------------
// 0: meta (cntNZ, cntF, cntA)
// 1K: scale(256f), 2K: shift(256f), 3K: cf(256f)
// 8K: cntM[512], 12K: baseA[512], 16K: baseF[512]
// 32K: Bwa packed (K=256) = 128KB; 256K: Bwf packed (K=768) = 384KB
// 1M: fusedIdx (512KB), 1.5M: audioIdx (512KB)
// 8M: bn_s (NB2*256 f32), 16M: bn_q
// 32M: gf bf16 (NN*256 = 64MB)

__device__ __forceinline__ ushort f2bf(float f) {
    uint u = __float_as_uint(f);
    u += 0x7FFF + ((u >> 16) & 1);
    return (ushort)(u >> 16);
}
__device__ __forceinline__ uint pk2(float a, float b) {
    bf16x2 t;
    t[0] = (__bf16)a;
    t[1] = (__bf16)b;
    return __builtin_bit_cast(uint, t);
}
__device__ __forceinline__ bool mask_val(const unsigned char* m8, int flag, int i) {
    return flag ? (m8[(size_t)i * 4] != 0) : (m8[i] != 0);
}
// Packed B: chunk (kb=k>>5, ct=c>>4) = 512 contiguous ushorts in MFMA-lane
// order: lane = fg*16+fr, elem = k&7.
__device__ __forceinline__ size_t pack_off(int k, int c) {
    return (size_t)(((k >> 5) * 16 + (c >> 4)) * 512
                    + (((k >> 3) & 3) * 16 + (c & 15)) * 8 + (k & 7));
}

// Detect mask dtype: nonzero bytes at offset 1 (mod 4) in first NN bytes
// (safe region for both dtypes) => 1-byte bool.
__global__ void k_detect(const uint4* m128, int n, int* cntNZ) {
    __shared__ int cnt;
    if (threadIdx.x == 0) cnt = 0;
    __syncthreads();
    int local = 0;
    int nv = n >> 4;
    #pragma unroll 4
    for (int i = threadIdx.x; i < nv; i += 1024) {
        uint4 v = m128[i];
        if ((v.x | v.y | v.z | v.w) & 0x0000FF00u) local = 1;
    }
    if (local) atomicAdd(&cnt, 1);
    __syncthreads();
    if (threadIdx.x == 0) *cntNZ = cnt;
}

// Per-256-row-chunk audio count.
__global__ void k_count(const unsigned char* m8, const int* cntNZp, int* cntM) {
    int flag = (*cntNZp == 0) ? 1 : 0;
    int t = threadIdx.x;
    bool m = mask_val(m8, flag, blockIdx.x * 256 + t);
    unsigned long long bal = __ballot(m);
    __shared__ int wsum[4];
    if ((t & 63) == 0) wsum[t >> 6] = __popcll(bal);
    __syncthreads();
    if (t == 0) cntM[blockIdx.x] = wsum[0] + wsum[1] + wsum[2] + wsum[3];
}

// Exclusive scan of chunk counts -> bases + totals. One block, 512 threads.
__global__ void k_scan(const int* __restrict__ cntM, int* __restrict__ meta,
                       int* __restrict__ baseA, int* __restrict__ baseF) {
    __shared__ int sA[512], sF[512];
    int t = threadIdx.x;
    int a = cntM[t], f = 256 - a;
    sA[t] = a; sF[t] = f;
    __syncthreads();
    for (int off = 1; off < 512; off <<= 1) {
        int va = (t >= off) ? sA[t - off] : 0;
        int vf = (t >= off) ? sF[t - off] : 0;
        __syncthreads();
        sA[t] += va; sF[t] += vf;
        __syncthreads();
    }
    baseA[t] = sA[t] - a;
    baseF[t] = sF[t] - f;
    if (t == 511) { meta[2] = sA[511]; meta[1] = sF[511]; }
}

// Stable partition fill.
__global__ void k_fill(const unsigned char* m8, const int* cntNZp,
                       const int* __restrict__ baseA, const int* __restrict__ baseF,
                       int* __restrict__ audioIdx, int* __restrict__ fusedIdx) {
    int flag = (*cntNZp == 0) ? 1 : 0;
    int blk = blockIdx.x, t = threadIdx.x;
    int row = blk * 256 + t;
    bool m = mask_val(m8, flag, row);
    unsigned long long bal = __ballot(m);
    int lane = t & 63, w = t >> 6;
    unsigned long long lt = (1ull << lane) - 1ull;
    int pA = __popcll(bal & lt);
    __shared__ int wA[4];
    if (lane == 0) wA[w] = __popcll(bal);
    __syncthreads();
    int offA = 0;
    for (int i = 0; i < w; ++i) offA += wA[i];
    int offF = w * 64 - offA;
    int pF = lane - pA;
    if (m) audioIdx[baseA[blk] + offA + pA] = row;
    else   fusedIdx[baseF[blk] + offF + pF] = row;
}

// Packed weights. Bwa: k<256 -> Wa[k][c].
// Bwf (K=768, order [v_in|a_in]): k<512 -> (Wv@Wf_bot)[k][c];
// k in [512,768) -> Wf[k-512][c]. Block 1024 computes c_f.
__global__ void k_prep(const float* __restrict__ Wa, const float* __restrict__ Wf,
                       const float* __restrict__ Wv, const float* __restrict__ bv,
                       const float* __restrict__ bf_, ushort* __restrict__ Bwa,
                       ushort* __restrict__ Bwf, float* __restrict__ cf) {
    int c = threadIdx.x;
    int b = blockIdx.x;
    if (b < 256) {
        Bwa[pack_off(b, c)] = f2bf(Wa[b * 256 + c]);
    } else if (b < 512) {
        Bwf[pack_off(512 + (b - 256), c)] = f2bf(Wf[(b - 256) * 256 + c]);
    } else if (b < 1024) {
        int k = b - 512;
        const float* wr = Wv + k * 256;
        float acc = 0.f;
        #pragma unroll 8
        for (int j = 0; j < 256; ++j) acc += wr[j] * Wf[(256 + j) * 256 + c];
        Bwf[pack_off(k, c)] = f2bf(acc);
    } else {
        float acc = bf_[c];
        #pragma unroll 8
        for (int j = 0; j < 256; ++j) acc += bv[j] * Wf[(256 + j) * 256 + c];
        cf[c] = acc;
    }
}

// Visit-staged role-split GEMM. BM=64, BN=256, 512 thr, 8 waves (2x4).
// Fused: 3 visits (v_in lo / v_in hi / a_in*sim), each reading 1KB contiguous
// per row into a 32KB LDS panel (double-buffered, staging overlaps compute);
// 4 MFMA K-steps per visit. Audio: 1 visit (a_in). Sim: 8 rows/wave prologue.
// B-fragments direct from packed L2-resident buffers.
__global__ __launch_bounds__(512, 4) void k_main(
    const float* __restrict__ x, const int* __restrict__ meta,
    const int* __restrict__ fusedIdx, const int* __restrict__ audioIdx,
    const ushort* __restrict__ Bwa, const ushort* __restrict__ Bwf,
    const float* __restrict__ ba, const float* __restrict__ cf,
    ushort* __restrict__ gf, float* __restrict__ bn_s, float* __restrict__ bn_q)
{
    __shared__ ushort As[2][64 * 256];     // 2 x 32KB, xor-swizzled 16B slots
    __shared__ int ridxS[64];
    __shared__ float simS[64];
    __shared__ unsigned char validS[64];
    __shared__ float redS[256], redQ[256];

    const int tid = threadIdx.x;
    const int cntF = meta[1], cntA = meta[2];
    const int nbF = (cntF + 63) >> 6;
    const int nbA = (cntA + 63) >> 6;
    const int b = blockIdx.x;
    const bool isF = b < nbF;
    const int bb = isF ? b : b - nbF;

    if (!isF && bb >= nbA) {   // idle block: zero BN slots
        if (tid < 256) {
            bn_s[(size_t)b * 256 + tid] = 0.f;
            bn_q[(size_t)b * 256 + tid] = 0.f;
        }
        return;
    }

    const int cnt = isF ? cntF : cntA;
    const int* idxArr = isF ? fusedIdx : audioIdx;
    const int lane = tid & 63;
    const int w = tid >> 6, wr = w >> 2, wc = w & 3;
    const int fr = lane & 15, fg = lane >> 4;

    if (tid < 64) {
        int gpos = bb * 64 + tid;
        int ok = gpos < cnt;
        ridxS[tid] = ok ? idxArr[gpos] : 0;
        validS[tid] = ok;
        simS[tid] = 1.f;
    }
    if (tid < 256) { redS[tid] = 0.f; redQ[tid] = 0.f; }
    __syncthreads();

    // staging ids: 8 threads/row, 32 floats (1..of 8 f32x4) each
    const int sr2 = tid >> 3, kq = tid & 7;
    const float* xrow = x + (size_t)ridxS[sr2] * 2048;
    const float sVf = validS[sr2] ? 1.f : 0.f;

    f32x4 t0_, t1_, t2_, t3_, t4_, t5_, t6_, t7_;
    auto loadV = [&](int baseF_) {
        const f32x4* src = (const f32x4*)(xrow + baseF_) + kq * 8;
        t0_ = src[0]; t1_ = src[1]; t2_ = src[2]; t3_ = src[3];
        t4_ = src[4]; t5_ = src[5]; t6_ = src[6]; t7_ = src[7];
    };
    auto storeV = [&](int buf, float scl) {
        ushort* dst = As[buf] + sr2 * 256;
        int sx = sr2 & 7;
        uint4 q;
        q.x = pk2(t0_.x * scl, t0_.y * scl); q.y = pk2(t0_.z * scl, t0_.w * scl);
        q.z = pk2(t1_.x * scl, t1_.y * scl); q.w = pk2(t1_.z * scl, t1_.w * scl);
        *(uint4*)(dst + (((kq * 4 + 0) ^ sx) << 3)) = q;
        q.x = pk2(t2_.x * scl, t2_.y * scl); q.y = pk2(t2_.z * scl, t2_.w * scl);
        q.z = pk2(t3_.x * scl, t3_.y * scl); q.w = pk2(t3_.z * scl, t3_.w * scl);
        *(uint4*)(dst + (((kq * 4 + 1) ^ sx) << 3)) = q;
        q.x = pk2(t4_.x * scl, t4_.y * scl); q.y = pk2(t4_.z * scl, t4_.w * scl);
        q.z = pk2(t5_.x * scl, t5_.y * scl); q.w = pk2(t5_.z * scl, t5_.w * scl);
        *(uint4*)(dst + (((kq * 4 + 2) ^ sx) << 3)) = q;
        q.x = pk2(t6_.x * scl, t6_.y * scl); q.y = pk2(t6_.z * scl, t6_.w * scl);
        q.z = pk2(t7_.x * scl, t7_.y * scl); q.w = pk2(t7_.z * scl, t7_.w * scl);
        *(uint4*)(dst + (((kq * 4 + 3) ^ sx) << 3)) = q;
    };

    const ushort* bBase = (isF ? Bwf : Bwa) + ((size_t)(wc * 4) << 9) + (lane << 3);
    const int r0 = wr * 32 + fr, r1 = r0 + 16;
    const ushort* prd0 = As[0] + r0 * 256;  // buf selected by pointer below
    const int sx0 = r0 & 7, sx1 = r1 & 7;

    f32x4 acc[2][4];
    #pragma unroll
    for (int m = 0; m < 2; ++m)
        #pragma unroll
        for (int n = 0; n < 4; ++n) acc[m][n] = (f32x4){0.f, 0.f, 0.f, 0.f};

    auto compute4 = [&](int buf, int visit) {
        const ushort* p0 = As[buf] + r0 * 256;
        const ushort* p1 = As[buf] + r1 * 256;
        #pragma unroll
        for (int st = 0; st < 4; ++st) {
            #pragma unroll
            for (int kk = 0; kk < 2; ++kk) {
                int sl = st * 8 + kk * 4 + fg;
                bf16x8 a0 = *(const bf16x8*)(p0 + ((sl ^ sx0) << 3));
                bf16x8 a1 = *(const bf16x8*)(p1 + ((sl ^ sx1) << 3));
                int kb = (visit * 4 + st) * 2 + kk;
                #pragma unroll
                for (int n = 0; n < 4; ++n) {
                    bf16x8 bv = *(const bf16x8*)(bBase + ((size_t)(kb * 16 + n) << 9));
                    acc[0][n] = __builtin_amdgcn_mfma_f32_16x16x32_bf16(a0, bv, acc[0][n], 0, 0, 0);
                    acc[1][n] = __builtin_amdgcn_mfma_f32_16x16x32_bf16(a1, bv, acc[1][n], 0, 0, 0);
                }
            }
        }
    };

    if (isF) {
        loadV(512);                       // visit 0: v_in lo (sim-independent)
        // ---- sim prologue: 8 rows per wave, 4KB contiguous per row ----
        #pragma unroll 2
        for (int rr = 0; rr < 8; ++rr) {
            int r = w * 8 + rr;
            const f32x4* p = (const f32x4*)(x + (size_t)ridxS[r] * 2048 + 1024);
            f32x4 a0 = p[lane], a1 = p[lane + 64];
            f32x4 v0 = p[lane + 128], v1 = p[lane + 192];
            float dot = a0.x * v0.x + a0.y * v0.y + a0.z * v0.z + a0.w * v0.w
                      + a1.x * v1.x + a1.y * v1.y + a1.z * v1.z + a1.w * v1.w;
            float na = a0.x * a0.x + a0.y * a0.y + a0.z * a0.z + a0.w * a0.w
                     + a1.x * a1.x + a1.y * a1.y + a1.z * a1.z + a1.w * a1.w;
            float nv = v0.x * v0.x + v0.y * v0.y + v0.z * v0.z + v0.w * v0.w
                     + v1.x * v1.x + v1.y * v1.y + v1.z * v1.z + v1.w * v1.w;
            #pragma unroll
            for (int off = 32; off; off >>= 1) {
                dot += __shfl_xor(dot, off);
                na  += __shfl_xor(na,  off);
                nv  += __shfl_xor(nv,  off);
            }
            if (lane == 0)
                simS[r] = dot / fmaxf(sqrtf(na * nv), 1e-8f);
        }
        storeV(0, sVf);
        loadV(768);                       // visit 1: v_in hi
        __syncthreads();                  // buf0 + simS ready
        compute4(0, 0);
        storeV(1, sVf);
        float sAf = validS[sr2] ? simS[sr2] : 0.f;
        __syncthreads();                  // buf1 ready
        loadV(0);                         // visit 2: a_in (scaled at store)
        compute4(1, 1);
        storeV(0, sAf);
        __syncthreads();                  // buf0(v2) ready
        compute4(0, 2);
    } else {
        loadV(0);                         // a_in
        storeV(0, sVf);
        __syncthreads();
        compute4(0, 0);
    }

    // ---- epilogue: bias, gf scatter, BN partials ----
    const int colLo = wc * 64 + fr;
    const float* biasp = isF ? cf : ba;
    float bN[4];
    #pragma unroll
    for (int n = 0; n < 4; ++n) bN[n] = biasp[colLo + n * 16];

    float cs[4] = {0.f, 0.f, 0.f, 0.f}, cq[4] = {0.f, 0.f, 0.f, 0.f};
    #pragma unroll
    for (int m = 0; m < 2; ++m) {
        #pragma unroll
        for (int j = 0; j < 4; ++j) {
            int rloc = wr * 32 + m * 16 + fg * 4 + j;
            if (validS[rloc]) {
                ushort* grow = gf + (size_t)ridxS[rloc] * 256;
                #pragma unroll
                for (int n = 0; n < 4; ++n) {
                    float g = acc[m][n][j] + bN[n];
                    grow[colLo + n * 16] = f2bf(g);
                    cs[n] += g;
                    cq[n] += g * g;
                }
            }
        }
    }
    #pragma unroll
    for (int n = 0; n < 4; ++n) {
        atomicAdd(&redS[colLo + n * 16], cs[n]);
        atomicAdd(&redQ[colLo + n * 16], cq[n]);
    }
    __syncthreads();
    if (tid < 256) {
        bn_s[(size_t)b * 256 + tid] = redS[tid];
        bn_q[(size_t)b * 256 + tid] = redQ[tid];
    }
}

// Finalize BN stats: one block per channel, reduce NB2 block partials.
__global__ void k_stats(const float* __restrict__ bn_s, const float* __restrict__ bn_q,
                        const float* __restrict__ gamma, const float* __restrict__ beta,
                        float* __restrict__ scale, float* __restrict__ shift) {
    int c = blockIdx.x;
    int t = threadIdx.x;
    float s = 0.f, q = 0.f;
    for (int r = t; r < NB2; r += 256) {
        s += bn_s[(size_t)r * 256 + c];
        q += bn_q[(size_t)r * 256 + c];
    }
    __shared__ float ss[256], qq[256];
    ss[t] = s; qq[t] = q;
    __syncthreads();
    for (int off = 128; off; off >>= 1) {
        if (t < off) { ss[t] += ss[t + off]; qq[t] += qq[t + off]; }
        __syncthreads();
    }
    if (t == 0) {
        float mu  = ss[0] / 131072.f;
        float var = qq[0] / 131072.f - mu * mu;
        float sc = gamma[c] * rsqrtf(var + 1e-5f);
        scale[c] = sc;
        shift[c] = beta[c] - mu * sc;
    }
}

// Normalize + ReLU + 256->2 FC. Two rows per wave (uint4 = 8 bf16/lane).
__global__ void k_out(const ushort* __restrict__ gf, const float* __restrict__ scale,
                      const float* __restrict__ shift, const float* __restrict__ Wfc,
                      const float* __restrict__ bfc, float* __restrict__ out) {
    int wid = threadIdx.x >> 6;
    int lane = threadIdx.x & 63;
    int hl = lane & 31;
    int i = blockIdx.x * 8 + wid * 2 + (lane >> 5);
    uint4 gv = ((const uint4*)(gf + (size_t)i * 256))[hl];
    int c0 = hl * 8;
    float g[8];
    g[0] = __uint_as_float(gv.x << 16); g[1] = __uint_as_float(gv.x & 0xFFFF0000u);
    g[2] = __uint_as_float(gv.y << 16); g[3] = __uint_as_float(gv.y & 0xFFFF0000u);
    g[4] = __uint_as_float(gv.z << 16); g[5] = __uint_as_float(gv.z & 0xFFFF0000u);
    g[6] = __uint_as_float(gv.w << 16); g[7] = __uint_as_float(gv.w & 0xFFFF0000u);
    float p0 = 0.f, p1 = 0.f;
    #pragma unroll
    for (int j = 0; j < 2; ++j) {
        f32x4 sc = *(const f32x4*)(scale + c0 + j * 4);
        f32x4 sh = *(const f32x4*)(shift + c0 + j * 4);
        f32x4 w0 = *(const f32x4*)(Wfc + (c0 + j * 4) * 2);
        f32x4 w1 = *(const f32x4*)(Wfc + (c0 + j * 4) * 2 + 4);
        float y0 = fmaxf(g[j * 4 + 0] * sc.x + sh.x, 0.f);
        float y1 = fmaxf(g[j * 4 + 1] * sc.y + sh.y, 0.f);
        float y2 = fmaxf(g[j * 4 + 2] * sc.z + sh.z, 0.f);
        float y3 = fmaxf(g[j * 4 + 3] * sc.w + sh.w, 0.f);
        p0 += y0 * w0.x + y1 * w0.z + y2 * w1.x + y3 * w1.z;
        p1 += y0 * w0.y + y1 * w0.w + y2 * w1.y + y3 * w1.w;
    }
    #pragma unroll
    for (int off = 16; off; off >>= 1) {
        p0 += __shfl_xor(p0, off);
        p1 += __shfl_xor(p1, off);
    }
    if (hl == 0) {
        out[(size_t)i * 2]     = p0 + bfc[0];
        out[(size_t)i * 2 + 1] = p1 + bfc[1];
    }
}

extern "C" void kernel_launch(void* const* d_in, const int* in_sizes, int n_in,
                              void* d_out, int out_size, void* d_ws, size_t ws_size,
                              hipStream_t stream) {
    const float* x          = (const float*)d_in[0];
    const unsigned char* mk = (const unsigned char*)d_in[1];
    const float* Wa  = (const float*)d_in[2];
    const float* ba  = (const float*)d_in[3];
    const float* Wv  = (const float*)d_in[4];
    const float* bv  = (const float*)d_in[5];
    const float* Wf  = (const float*)d_in[6];
    const float* bf  = (const float*)d_in[7];
    const float* gamma = (const float*)d_in[8];
    const float* beta  = (const float*)d_in[9];
    const float* Wfc = (const float*)d_in[10];
    const float* bfc = (const float*)d_in[11];
    float* out = (float*)d_out;

    char* ws = (char*)d_ws;
    int*    meta   = (int*)ws;                       // cntNZ, cntF, cntA
    float*  scale  = (float*)(ws + 1024);
    float*  shift  = (float*)(ws + 2048);
    float*  cf     = (float*)(ws + 3072);
    int*    cntM   = (int*)(ws + 8192);
    int*    baseA  = (int*)(ws + 12288);
    int*    baseF  = (int*)(ws + 16384);
    ushort* Bwa    = (ushort*)(ws + 32768);
    ushort* Bwf    = (ushort*)(ws + 262144);
    int*    fusedIdx = (int*)(ws + (1u << 20));
    int*    audioIdx = (int*)(ws + (1u << 20) + (512u << 10));
    float*  bn_s   = (float*)(ws + (8u << 20));
    float*  bn_q   = (float*)(ws + (16u << 20));
    ushort* gf     = (ushort*)(ws + (32u << 20));

    int n = in_sizes[1];  // NN

    k_detect<<<1, 1024, 0, stream>>>((const uint4*)mk, n, meta);
    k_count<<<512, 256, 0, stream>>>(mk, meta, cntM);
    k_scan<<<1, 512, 0, stream>>>(cntM, meta, baseA, baseF);
    k_fill<<<512, 256, 0, stream>>>(mk, meta, baseA, baseF, audioIdx, fusedIdx);
    k_prep<<<1025, 256, 0, stream>>>(Wa, Wf, Wv, bv, bf, Bwa, Bwf, cf);
    k_main<<<NB2, 512, 0, stream>>>(x, meta, fusedIdx, audioIdx, Bwa, Bwf, ba, cf,
                                    gf, bn_s, bn_q);
    k_stats<<<256, 256, 0, stream>>>(bn_s, bn_q, gamma, beta, scale, shift);
    k_out<<<NN / 8, 256, 0, stream>>>(gf, scale, shift, Wfc, bfc, out);
}